// Round 1
// baseline (525.296 us; speedup 1.0000x reference)
//
#include <hip/hip_runtime.h>
#include <hip/hip_bf16.h>
#include <stdint.h>

typedef __attribute__((ext_vector_type(8))) short short8;
typedef __attribute__((ext_vector_type(4))) float f32x4;
typedef __attribute__((ext_vector_type(4))) unsigned int u32x4;

#define SEQ      8192
#define DHEAD    64
#define WIN      128
#define NWIN     64
#define NOUTW    62
#define KROWS    384
#define CH_ROWS  96
#define NCHUNK   4
#define T_PER_CH 6
#define NTILE    24

// LDS regions (bytes): Qh 16K | Ql 16K | Kh 12K | Kl 12K = 56 KB
#define QH_OFF 0
#define QL_OFF 16384
#define KH_OFF 32768
#define KL_OFF 45056
#define LDS_BYTES 57344

// XOR swizzle on 16B granules within each row (row stride 128B) so that a
// 16-lane column-slice ds_read_b128 spreads over all 32 banks (2-way = free).
__device__ __forceinline__ unsigned int swz(int row, int c16) {
    return (unsigned int)(row * 128 + ((c16 ^ (row & 7)) << 4));
}

__device__ __forceinline__ unsigned short bf16_rne(float f) {
    unsigned int u = __builtin_bit_cast(unsigned int, f);
    u += 0x7FFFu + ((u >> 16) & 1u);
    return (unsigned short)(u >> 16);
}

// fp32 -> (hi bf16, lo bf16) split; hi + lo reproduces fp32 to ~2^-17 rel.
__device__ __forceinline__ void split8(const float* v, u32x4* hi, u32x4* lo) {
    u32x4 h, l;
    #pragma unroll
    for (int i = 0; i < 4; ++i) {
        float f0 = v[2 * i], f1 = v[2 * i + 1];
        unsigned short h0 = bf16_rne(f0), h1 = bf16_rne(f1);
        float r0 = f0 - __builtin_bit_cast(float, (unsigned int)h0 << 16);
        float r1 = f1 - __builtin_bit_cast(float, (unsigned int)h1 << 16);
        unsigned short l0 = bf16_rne(r0), l1 = bf16_rne(r1);
        h[i] = (unsigned int)h0 | ((unsigned int)h1 << 16);
        l[i] = (unsigned int)l0 | ((unsigned int)l1 << 16);
    }
    *hi = h; *lo = l;
}

__global__ __launch_bounds__(512, 2)
void local_attn_kernel(const float* __restrict__ q, const float* __restrict__ k,
                       float* __restrict__ out) {
    __shared__ char smem[LDS_BYTES];
    const int tid = threadIdx.x;
    const int blk = blockIdx.x;
    const int bh  = blk / NOUTW;
    const int ow  = blk - bh * NOUTW;
    // remaining windows = [0..63] minus {2, 34}
    const int wi = ow + (ow >= 2 ? 1 : 0) + (ow >= 33 ? 1 : 0);
    const int krow0 = (wi - 1) * WIN;   // global k row of j=0

    const float* qblk = q + ((size_t)bh * SEQ + (size_t)wi * WIN) * DHEAD;
    const float* kbh  = k + (size_t)bh * SEQ * DHEAD;

    // ---- stage Q (scaled by d^-1/2, split hi/lo) : 128 rows x 8 granules ----
    #pragma unroll
    for (int it = 0; it < 2; ++it) {
        int g = tid + it * 512;            // granule: row=g>>3, c16=g&7
        int row = g >> 3, c16 = g & 7;
        float v[8];
        *(f32x4*)(v)     = *(const f32x4*)(qblk + g * 8);
        *(f32x4*)(v + 4) = *(const f32x4*)(qblk + g * 8 + 4);
        #pragma unroll
        for (int i = 0; i < 8; ++i) v[i] *= 0.125f;
        u32x4 hi, lo;
        split8(v, &hi, &lo);
        unsigned int off = swz(row, c16);
        *(u32x4*)(smem + QH_OFF + off) = hi;
        *(u32x4*)(smem + QL_OFF + off) = lo;
    }

    // ---- K chunk stager: 96 rows x 8 granules, zero-fill out-of-range rows ----
    auto stageK = [&](int c) {
        #pragma unroll
        for (int it = 0; it < 2; ++it) {
            int g = tid + it * 512;
            if (g < CH_ROWS * 8) {
                int row = g >> 3, c16 = g & 7;
                int gk = krow0 + c * CH_ROWS + row;
                unsigned int off = swz(row, c16);
                u32x4 hi = (u32x4)(0u), lo = (u32x4)(0u);
                if (gk >= 0 && gk < SEQ) {
                    float v[8];
                    const float* src = kbh + (size_t)gk * DHEAD + c16 * 8;
                    *(f32x4*)(v)     = *(const f32x4*)(src);
                    *(f32x4*)(v + 4) = *(const f32x4*)(src + 4);
                    split8(v, &hi, &lo);
                }
                *(u32x4*)(smem + KH_OFF + off) = hi;
                *(u32x4*)(smem + KL_OFF + off) = lo;
            }
        }
    };

    stageK(0);
    __syncthreads();

    const int lane = tid & 63;
    const int wv   = tid >> 6;        // wave 0..7 -> rows [wv*16, wv*16+16)
    const int rq   = lane >> 4;       // k-granule / row-quad index
    const int rc   = lane & 15;       // col within tile / row within frag

    // A fragments (Q), reused across all 24 column tiles
    const int rowq = wv * 16 + rc;
    short8 a_h0 = *(const short8*)(smem + QH_OFF + swz(rowq, rq));
    short8 a_h1 = *(const short8*)(smem + QH_OFF + swz(rowq, 4 + rq));
    short8 a_l0 = *(const short8*)(smem + QL_OFF + swz(rowq, rq));
    short8 a_l1 = *(const short8*)(smem + QL_OFF + swz(rowq, 4 + rq));

    f32x4 acc[NTILE];
    #pragma unroll
    for (int t = 0; t < NTILE; ++t) acc[t] = (f32x4)(0.0f);

    #pragma unroll
    for (int c = 0; c < NCHUNK; ++c) {
        #pragma unroll
        for (int t = 0; t < T_PER_CH; ++t) {
            const int rowk = t * 16 + rc;
            short8 b_h0 = *(const short8*)(smem + KH_OFF + swz(rowk, rq));
            short8 b_h1 = *(const short8*)(smem + KH_OFF + swz(rowk, 4 + rq));
            short8 b_l0 = *(const short8*)(smem + KL_OFF + swz(rowk, rq));
            short8 b_l1 = *(const short8*)(smem + KL_OFF + swz(rowk, 4 + rq));
            f32x4 a = acc[c * T_PER_CH + t];
            // 3-term split product: hi*hi + hi*lo + lo*hi (lo*lo ~2^-18, dropped)
            a = __builtin_amdgcn_mfma_f32_16x16x32_bf16(a_h0, b_h0, a, 0, 0, 0);
            a = __builtin_amdgcn_mfma_f32_16x16x32_bf16(a_h1, b_h1, a, 0, 0, 0);
            a = __builtin_amdgcn_mfma_f32_16x16x32_bf16(a_h0, b_l0, a, 0, 0, 0);
            a = __builtin_amdgcn_mfma_f32_16x16x32_bf16(a_h1, b_l1, a, 0, 0, 0);
            a = __builtin_amdgcn_mfma_f32_16x16x32_bf16(a_l0, b_h0, a, 0, 0, 0);
            a = __builtin_amdgcn_mfma_f32_16x16x32_bf16(a_l1, b_h1, a, 0, 0, 0);
            acc[c * T_PER_CH + t] = a;
        }
        if (c < NCHUNK - 1) {
            __syncthreads();
            stageK(c + 1);
            __syncthreads();
        }
    }

    // ---- mask out-of-range windows (block-uniform) ----
    if (wi == 0) {
        #pragma unroll
        for (int t = 0; t < 8; ++t)
            #pragma unroll
            for (int r = 0; r < 4; ++r) acc[t][r] = -1e30f;
    }
    if (wi == NWIN - 1) {
        #pragma unroll
        for (int t = 16; t < 24; ++t)
            #pragma unroll
            for (int r = 0; r < 4; ++r) acc[t][r] = -1e30f;
    }

    // ---- softmax over 384 cols; row r held by 16-lane group (lane>>4)=r>>2 ----
    float mx[4] = {-3e38f, -3e38f, -3e38f, -3e38f};
    #pragma unroll
    for (int t = 0; t < NTILE; ++t)
        #pragma unroll
        for (int r = 0; r < 4; ++r) mx[r] = fmaxf(mx[r], acc[t][r]);
    #pragma unroll
    for (int m = 1; m <= 8; m <<= 1)
        #pragma unroll
        for (int r = 0; r < 4; ++r) mx[r] = fmaxf(mx[r], __shfl_xor(mx[r], m, 64));

    float sm[4] = {0.f, 0.f, 0.f, 0.f};
    #pragma unroll
    for (int t = 0; t < NTILE; ++t)
        #pragma unroll
        for (int r = 0; r < 4; ++r) {
            float e = __expf(acc[t][r] - mx[r]);
            acc[t][r] = e;
            sm[r] += e;
        }
    #pragma unroll
    for (int m = 1; m <= 8; m <<= 1)
        #pragma unroll
        for (int r = 0; r < 4; ++r) sm[r] += __shfl_xor(sm[r], m, 64);

    float inv[4];
    #pragma unroll
    for (int r = 0; r < 4; ++r) inv[r] = 1.0f / sm[r];

    // ---- store: lanes 0..15 write 64B-contiguous column runs ----
    float* oblk = out + (size_t)(bh * NOUTW + ow) * WIN * KROWS;
    const int orow = wv * 16 + rq * 4;
    #pragma unroll
    for (int t = 0; t < NTILE; ++t)
        #pragma unroll
        for (int r = 0; r < 4; ++r)
            oblk[(size_t)(orow + r) * KROWS + t * 16 + rc] = acc[t][r] * inv[r];
}

extern "C" void kernel_launch(void* const* d_in, const int* in_sizes, int n_in,
                              void* d_out, int out_size, void* d_ws, size_t ws_size,
                              hipStream_t stream) {
    const float* q = (const float*)d_in[0];
    const float* k = (const float*)d_in[1];
    float* out = (float*)d_out;
    const int nblocks = 32 * NOUTW;   // (B*H) * remaining windows = 1984
    local_attn_kernel<<<dim3(nblocks), dim3(512), 0, stream>>>(q, k, out);
}